// Round 4
// baseline (977.875 us; speedup 1.0000x reference)
//
#include <hip/hip_runtime.h>
#include <stdint.h>

typedef __attribute__((ext_vector_type(8)))  short   short8;
typedef __attribute__((ext_vector_type(8)))  unsigned short ushort8;
typedef __attribute__((ext_vector_type(8)))  __bf16  bf16x8;
typedef __attribute__((ext_vector_type(4)))  float   floatx4;
typedef __attribute__((ext_vector_type(4)))  unsigned short ushort4v;

#define AS1 __attribute__((address_space(1)))
#define AS3 __attribute__((address_space(3)))

__device__ __forceinline__ unsigned short f2bf(float f) {
  unsigned u = __builtin_bit_cast(unsigned, f);
  u = (u + 0x7FFFu + ((u >> 16) & 1u)) >> 16;   // RNE
  return (unsigned short)u;
}
__device__ __forceinline__ float bf2f(unsigned short h) {
  unsigned u = ((unsigned)h) << 16;
  return __builtin_bit_cast(float, u);
}

// ---------------- f32 -> bf16 convert (n multiple of 1024) ----------------
__global__ __launch_bounds__(256) void convert_bf16(const float* __restrict__ src,
                                                    unsigned short* __restrict__ dst,
                                                    int n) {
  int i = (blockIdx.x * 256 + threadIdx.x) * 4;
  if (i >= n) return;
  float4 v = *(const float4*)(src + i);
  ushort4v o;
  o.x = f2bf(v.x); o.y = f2bf(v.y); o.z = f2bf(v.z); o.w = f2bf(v.w);
  *(ushort4v*)(dst + i) = o;
}

// ---------------- int64-vs-int32 id layout detection ----------------
__global__ __launch_bounds__(256) void detect_i64(const int* __restrict__ idbuf,
                                                  int* __restrict__ flag) {
  int v = 0;
  for (int i = threadIdx.x; i < 2048; i += 256) v |= idbuf[2 * i + 1];
  if (v != 0) atomicOr(flag, 1);
}

// ---------------- gather rows of emb -> bf16 x ----------------
__global__ __launch_bounds__(256) void gather_embed(const int* __restrict__ ids,
                                                    const float* __restrict__ emb,
                                                    unsigned short* __restrict__ xbf,
                                                    const int* __restrict__ flag) {
  int i = blockIdx.x;                      // 0..4095 (b*256+s)
  int row = (*flag != 0) ? ids[i] : ids[2 * i];   // int32 vs int64 layout
  const float* src = emb + (size_t)row * 1024 + threadIdx.x * 4;
  float4 v = *(const float4*)src;
  ushort4v o;
  o.x = f2bf(v.x); o.y = f2bf(v.y); o.z = f2bf(v.z); o.w = f2bf(v.w);
  *(ushort4v*)(xbf + (size_t)i * 1024 + threadIdx.x * 4) = o;
}

// ---------------- bf16 GEMM  C[M,N] = A[M,K] * B[N,K]^T  (f32 out) ----------------
__global__ __launch_bounds__(256) void gemm_bt(const unsigned short* __restrict__ A,
                                               const unsigned short* __restrict__ B,
                                               float* __restrict__ C,
                                               int M, int N, int K) {
  __shared__ unsigned short lA[128 * 64];
  __shared__ unsigned short lB[128 * 64];
  const int nwg  = gridDim.x;
  const int wgid = blockIdx.x;
  const int q    = nwg >> 3;                       // XCD-aware swizzle (nwg % 8 == 0)
  const int swz  = (wgid & 7) * q + (wgid >> 3);
  const int ntx  = N >> 7;
  const int bx   = swz % ntx;
  const int by   = swz / ntx;
  const int tid  = threadIdx.x;
  const int lane = tid & 63;
  const int w    = tid >> 6;
  const int wr   = w >> 1, wc = w & 1;

  floatx4 acc[4][4];
#pragma unroll
  for (int m = 0; m < 4; ++m)
#pragma unroll
    for (int n = 0; n < 4; ++n) acc[m][n] = (floatx4){0.f, 0.f, 0.f, 0.f};

  const size_t rowA0 = (size_t)by * 128;
  const size_t colB0 = (size_t)bx * 128;

  for (int k0 = 0; k0 < K; k0 += 64) {
#pragma unroll
    for (int p = 0; p < 4; ++p) {
      int cc = p * 256 + tid;       // 16B chunk id, 0..1023
      int r  = cc >> 3;             // tile row 0..127
      int c8 = cc & 7;              // 16B chunk within row
      const unsigned short* srcA = A + (rowA0 + r) * K + k0 + c8 * 8;
      const unsigned short* srcB = B + (colB0 + r) * K + k0 + c8 * 8;
      __builtin_amdgcn_global_load_lds((const AS1 unsigned int*)srcA,
                                       (AS3 unsigned int*)&lA[cc * 8], 16, 0, 0);
      __builtin_amdgcn_global_load_lds((const AS1 unsigned int*)srcB,
                                       (AS3 unsigned int*)&lB[cc * 8], 16, 0, 0);
    }
    __syncthreads();
#pragma unroll
    for (int kk = 0; kk < 2; ++kk) {
      const int kofs = kk * 32 + (lane >> 4) * 8;
      bf16x8 af[4], bfv[4];
#pragma unroll
      for (int m = 0; m < 4; ++m) {
        int r = wr * 64 + m * 16 + (lane & 15);
        af[m] = *(const bf16x8*)&lA[r * 64 + kofs];
      }
#pragma unroll
      for (int n = 0; n < 4; ++n) {
        int r = wc * 64 + n * 16 + (lane & 15);
        bfv[n] = *(const bf16x8*)&lB[r * 64 + kofs];
      }
#pragma unroll
      for (int m = 0; m < 4; ++m)
#pragma unroll
        for (int n = 0; n < 4; ++n)
          acc[m][n] = __builtin_amdgcn_mfma_f32_16x16x32_bf16(af[m], bfv[n], acc[m][n], 0, 0, 0);
    }
    __syncthreads();
  }

#pragma unroll
  for (int m = 0; m < 4; ++m) {
#pragma unroll
    for (int j = 0; j < 4; ++j) {
      size_t row = rowA0 + wr * 64 + m * 16 + ((lane >> 4) * 4 + j);
      float* crow = C + row * (size_t)N + colB0 + wc * 64 + (lane & 15);
#pragma unroll
      for (int n = 0; n < 4; ++n) crow[n * 16] = acc[m][n][j];
    }
  }
}

// ---------------- recurrence: h_t = tanh(xin_t + h_{t-1} @ w_hh^T) ----------------
// 256 WGs = 16 batches x 16 slices of 64 output rows. 512 threads/WG (8 waves).
// Thread (o=tid&63, kc=tid>>6) holds w_hh[slice*64+o][kc*128 .. +128) as f32 in
// regs (128 VGPRs, pinned). Sync: data-as-flag (hs NaN-prefilled, each slot
// written once, device-coherent stores; consumers poll the data itself).
// NO per-step __syncthreads: waves publish partials + LDS flag; wave 0 polls
// flags and runs the tail while waves 1-7 already poll the next step's h.
__global__ __launch_bounds__(512, 2) void rnn_step_all(const float* __restrict__ xin,
                                                       const unsigned short* __restrict__ whh_bf,
                                                       float* __restrict__ hs,
                                                       unsigned short* __restrict__ hs_bf) {
  const int b     = blockIdx.x >> 4;
  const int slice = blockIdx.x & 15;
  const int tid   = threadIdx.x;
  const int o     = tid & 63;     // lane within wave
  const int kc    = tid >> 6;     // wave id == k-chunk (128 wide)

  __shared__ __align__(16) float hl[1024];   // wave-private 128-fl regions
  __shared__ float red[2][512];              // double-buffered partials
  __shared__ unsigned lflag[2][8];           // per-wave completion flags

  if (tid < 16) lflag[tid >> 3][tid & 7] = 0;
  __syncthreads();                           // the only barrier (init)

  float wf[128];
  {
    const unsigned short* wrow = whh_bf + (size_t)(slice * 64 + o) * 1024 + kc * 128;
#pragma unroll
    for (int j = 0; j < 16; ++j) {
      ushort8 wv = *(const ushort8*)(wrow + j * 8);
#pragma unroll
      for (int e = 0; e < 8; ++e) wf[j * 8 + e] = bf2f(wv[e]);
    }
    // Pin all 128 weight values into VGPRs (round-2: without enough headroom
    // the compiler re-fetched weights every step; 512thr + bounds(512,2)
    // gives a 256-VGPR budget so this genuinely fits now).
#pragma unroll
    for (int j = 0; j < 128; ++j) asm volatile("" : "+v"(wf[j]));
  }

  const size_t bbase = (size_t)b * 256 * 1024;

  for (int t = 0; t < 256; ++t) {
    float s = 0.0f;
    if (tid < 64) s = xin[bbase + (size_t)t * 1024 + slice * 64 + o];  // prefetch

    if (t == 0) {
      hl[kc * 128 + o]      = 0.0f;          // zero own read region (wave-private)
      hl[kc * 128 + 64 + o] = 0.0f;
    } else {
      // wave kc polls its own 128 h-values (written once, NaN until then)
      const float* src = &hs[bbase + (size_t)(t - 1) * 1024 + (size_t)kc * 128];
      float v1, v2;
      do {
        v1 = __hip_atomic_load(src + o,      __ATOMIC_RELAXED, __HIP_MEMORY_SCOPE_AGENT);
        v2 = __hip_atomic_load(src + 64 + o, __ATOMIC_RELAXED, __HIP_MEMORY_SCOPE_AGENT);
      } while (__any((v1 != v1) | (v2 != v2)));
      hl[kc * 128 + o]      = v1;            // wave-private; lgkmcnt orders r-a-w
      hl[kc * 128 + 64 + o] = v2;
    }

    float a0 = 0.f, a1 = 0.f, a2 = 0.f, a3 = 0.f;
#pragma unroll
    for (int j4 = 0; j4 < 32; ++j4) {
      float4 hv = *(const float4*)&hl[kc * 128 + j4 * 4];   // uniform -> broadcast
      a0 += wf[j4 * 4 + 0] * hv.x; a1 += wf[j4 * 4 + 1] * hv.y;
      a2 += wf[j4 * 4 + 2] * hv.z; a3 += wf[j4 * 4 + 3] * hv.w;
    }
    red[t & 1][tid] = (a0 + a1) + (a2 + a3);
    asm volatile("s_waitcnt lgkmcnt(0)" ::: "memory");  // red write done before flag
    __builtin_amdgcn_sched_barrier(0);
    if (o == 0) lflag[t & 1][kc] = (unsigned)(t + 1);
    // waves 1..7 fall through to the next step's global poll here -> their
    // poll-detect overlaps wave 0's tail below.

    if (tid < 64) {
      // wave 0: wait for all 8 partial flags (fast LDS poll; ~0 in steady state)
      const volatile unsigned* fl = &lflag[t & 1][0];
      bool rdy;
      do {
        rdy = true;
#pragma unroll
        for (int k = 0; k < 8; ++k) rdy = rdy && (fl[k] >= (unsigned)(t + 1));
      } while (!rdy);
      __builtin_amdgcn_sched_barrier(0);
      asm volatile("" ::: "memory");
#pragma unroll
      for (int k2 = 0; k2 < 8; ++k2) s += red[t & 1][k2 * 64 + o];
      // fast tanh: 1 - 2/(e^{2s}+1)
      float e  = __expf(2.0f * s);
      float hv = 1.0f - 2.0f * __builtin_amdgcn_rcpf(e + 1.0f);
      size_t idx = bbase + (size_t)t * 1024 + (size_t)slice * 64 + o;
      __hip_atomic_store(&hs[idx], hv, __ATOMIC_RELAXED, __HIP_MEMORY_SCOPE_AGENT);
      hs_bf[idx] = f2bf(hv);        // plain store; consumed after kernel end
    }
  }
}

// ---------------- host launch ----------------
extern "C" void kernel_launch(void* const* d_in, const int* in_sizes, int n_in,
                              void* d_out, int out_size, void* d_ws, size_t ws_size,
                              hipStream_t stream) {
  const int*   ids  = (const int*)d_in[0];     // [16,256]
  const float* emb  = (const float*)d_in[1];   // [32000,1024]
  const float* w_hx = (const float*)d_in[2];   // [1024,1024]
  const float* w_hh = (const float*)d_in[3];   // [1024,1024]
  const float* w_yh = (const float*)d_in[4];   // [32000,1024]
  float*       out  = (float*)d_out;           // [16,256,32000]

  const int B = 16, S = 256, H = 1024, V = 32000;
  const int BS = B * S;

  char*  ws  = (char*)d_ws;
  size_t off = 0;
  auto alloc = [&](size_t bytes) {
    size_t cur = off;
    off += (bytes + 255) & ~(size_t)255;
    return (void*)(ws + cur);
  };

  unsigned short* whx_bf = (unsigned short*)alloc((size_t)H * H * 2);
  unsigned short* whh_bf = (unsigned short*)alloc((size_t)H * H * 2);
  unsigned short* wyh_bf = (unsigned short*)alloc((size_t)V * H * 2);
  unsigned short* x_bf   = (unsigned short*)alloc((size_t)BS * H * 2);
  float*          xin    = (float*)alloc((size_t)BS * H * 4);
  float*          hs     = (float*)alloc((size_t)BS * H * 4);
  unsigned short* hs_bf  = (unsigned short*)alloc((size_t)BS * H * 2);
  int*            dflag  = (int*)alloc(256);

  // Re-arm the NaN sentinel every call (replays would otherwise see stale
  // non-NaN h values and race ahead). 0xFF bytes -> every f32 is NaN.
  hipMemsetAsync(hs, 0xFF, (size_t)BS * H * 4, stream);
  hipMemsetAsync(dflag, 0, 256, stream);

  detect_i64<<<dim3(1), dim3(256), 0, stream>>>(ids, dflag);
  convert_bf16<<<dim3((H * H) / 1024), dim3(256), 0, stream>>>(w_hx, whx_bf, H * H);
  convert_bf16<<<dim3((H * H) / 1024), dim3(256), 0, stream>>>(w_hh, whh_bf, H * H);
  convert_bf16<<<dim3((V * H) / 1024), dim3(256), 0, stream>>>(w_yh, wyh_bf, V * H);
  gather_embed<<<dim3(BS), dim3(256), 0, stream>>>(ids, emb, x_bf, dflag);

  // xin = x @ w_hx^T : M=4096, N=1024, K=1024 -> 256 WGs
  gemm_bt<<<dim3((BS / 128) * (H / 128)), dim3(256), 0, stream>>>(x_bf, whx_bf, xin, BS, H, H);

  // sequential recurrence (persistent, data-as-flag sync, barrier-free steps)
  rnn_step_all<<<dim3(256), dim3(512), 0, stream>>>(xin, whh_bf, hs, hs_bf);

  // logits = hs @ w_yh^T : M=4096, N=32000, K=1024 -> 8000 WGs
  gemm_bt<<<dim3((BS / 128) * (V / 128)), dim3(256), 0, stream>>>(hs_bf, wyh_bf, out, BS, V, H);
}